// Round 14
// baseline (991.976 us; speedup 1.0000x reference)
//
#include <hip/hip_runtime.h>

#define Bc 16
#define Tc 16
#define Cc 512
#define Kc 64
#define Sc 196
#define KS (Kc*Sc)          // 12544
#define BKS (Bc*Kc*Sc)      // 200704
#define TBKS (Tc*BKS)       // 3211264
#define GFIN (16*64*512)    // 524288
#define PART_N (8*GFIN)     // 4194304
#define PX 256              // 16 rows * 16 cols per plane
#define PLB2 (Kc*PX)        // 16384 elems per b (now [px][k] layout, k fastest)
#define NUTT 110592         // 3*9*64*64

typedef __attribute__((ext_vector_type(8))) short bf16x8;
typedef __attribute__((ext_vector_type(4))) float f32x4;

__device__ __forceinline__ float sigmoid_f(float x) { return 1.f / (1.f + __expf(-x)); }
__device__ __forceinline__ float tanh_f(float x) { return 1.f - 2.f / (__expf(2.f * x) + 1.f); }

__device__ __forceinline__ float b2f(unsigned short u) {
    return __uint_as_float(((unsigned)u) << 16);
}
__device__ __forceinline__ unsigned short f2b(float f) {   // RNE
    unsigned u = __float_as_uint(f);
    return (unsigned short)((u + 0x7FFFu + ((u >> 16) & 1u)) >> 16);
}
__device__ __forceinline__ void split1(float f, unsigned short& h, unsigned short& l) {
    unsigned u = __float_as_uint(f);
    unsigned uh = u & 0xffff0000u;
    h = (unsigned short)(uh >> 16);
    float fl = f - __uint_as_float(uh);
    l = (unsigned short)(__float_as_uint(fl) >> 16);
}

// ---------------- prep W: split share_w [64][512] into bf16 hi/lo ----------------
__global__ __launch_bounds__(256) void k_prep_w(const float* __restrict__ w,
        unsigned short* __restrict__ wh, unsigned short* __restrict__ wl) {
    int idx = blockIdx.x * 256 + threadIdx.x;   // 32768 total
    unsigned short h, l;
    split1(w[idx], h, l);
    wh[idx] = h; wl[idx] = l;
}

// ---------------- prep U: Utt[g][tap][ko][ki] hi/lo from U[ko][ki][tap] ----------------
__global__ __launch_bounds__(256) void k_prep_u(const float* __restrict__ Uz,
        const float* __restrict__ Ur, const float* __restrict__ Uh,
        unsigned short* __restrict__ uth, unsigned short* __restrict__ utl) {
    int idx = blockIdx.x * 256 + threadIdx.x;   // NUTT total (grid 432)
    int ki = idx & 63;
    int ko = (idx >> 6) & 63;
    int gt = idx >> 12;        // g*9 + tap
    int tap = gt % 9, g = gt / 9;
    const float* U = (g == 0) ? Uz : (g == 1) ? Ur : Uh;
    float v = U[((size_t)ko * 64 + ki) * 9 + tap];
    unsigned short h, l;
    split1(v, h, l);
    uth[idx] = h; utl[idx] = l;
}

// ---------------- zero-init planes ----------------
__global__ __launch_bounds__(256) void k_init(float4* __restrict__ h32,
        float4* __restrict__ h16, float4* __restrict__ rh16) {
    const int i = blockIdx.x * 256 + threadIdx.x;   // grid 256
    const float4 z = make_float4(0.f, 0.f, 0.f, 0.f);
    h32[i] = z;
    if (i < 32768) { h16[i] = z; rh16[i] = z; }
}

// ---------------- conv1x1 via MFMA (unchanged structure), t0 fused; planes [px][k] ----------------
__global__ __launch_bounds__(512) void k_conv1x1(const float* __restrict__ x,
        const unsigned short* __restrict__ wh, const unsigned short* __restrict__ wl,
        const float* __restrict__ bias, float* __restrict__ wxb,
        float* __restrict__ assign0, float* __restrict__ hplane32,
        unsigned short* __restrict__ hplane16) {
    __shared__ unsigned short Xh[64 * 40];
    __shared__ unsigned short Xl[64 * 40];
    const int gs0 = blockIdx.x * 64;
    const int tid = threadIdx.x;
    const int wv = tid >> 6, lane = tid & 63;
    const int lg = lane >> 4, ln = lane & 15;
    const int mt = wv & 3, np = wv >> 2;
    const int gslS = tid & 63;
    const int c4S = (tid >> 6) * 4;
    const int gsS = gs0 + gslS;
    const int nS = gsS / Sc, sS = gsS - nS * Sc;
    const float* xcol = x + (size_t)nS * (Cc * Sc) + sS;
    const int colS = (((c4S >> 3) ^ ((gslS >> 3) & 3)) << 3) + (c4S & 7);
    const int kA = np * 32 + ln;
    const float bias0 = bias[kA], bias1 = bias[kA + 16];
    const int gsA = mt * 16 + ln;
    const int swzA = (gsA >> 3) & 3;

    float xr[4];
#pragma unroll
    for (int i = 0; i < 4; ++i) xr[i] = xcol[(size_t)(c4S + i) * Sc];

    f32x4 acc0 = {0.f, 0.f, 0.f, 0.f}, acc1 = {0.f, 0.f, 0.f, 0.f};
    for (int c0 = 0; c0 < Cc; c0 += 32) {
        __syncthreads();
        {
            ushort4 h, l;
            split1(xr[0], h.x, l.x); split1(xr[1], h.y, l.y);
            split1(xr[2], h.z, l.z); split1(xr[3], h.w, l.w);
            *(ushort4*)(Xh + gslS * 40 + colS) = h;
            *(ushort4*)(Xl + gslS * 40 + colS) = l;
        }
        __syncthreads();
        if (c0 + 32 < Cc) {
#pragma unroll
            for (int i = 0; i < 4; ++i) xr[i] = xcol[(size_t)(c0 + 32 + c4S + i) * Sc];
        }
        bf16x8 B0h = *(const bf16x8*)(wh + (size_t)kA * Cc + c0 + lg * 8);
        bf16x8 B0l = *(const bf16x8*)(wl + (size_t)kA * Cc + c0 + lg * 8);
        bf16x8 B1h = *(const bf16x8*)(wh + (size_t)(kA + 16) * Cc + c0 + lg * 8);
        bf16x8 B1l = *(const bf16x8*)(wl + (size_t)(kA + 16) * Cc + c0 + lg * 8);
        bf16x8 Af = *(const bf16x8*)(Xh + gsA * 40 + ((lg ^ swzA) << 3));
        bf16x8 Alo = *(const bf16x8*)(Xl + gsA * 40 + ((lg ^ swzA) << 3));
        acc0 = __builtin_amdgcn_mfma_f32_16x16x32_bf16(Af, B0h, acc0, 0, 0, 0);
        acc0 = __builtin_amdgcn_mfma_f32_16x16x32_bf16(Alo, B0h, acc0, 0, 0, 0);
        acc0 = __builtin_amdgcn_mfma_f32_16x16x32_bf16(Af, B0l, acc0, 0, 0, 0);
        acc1 = __builtin_amdgcn_mfma_f32_16x16x32_bf16(Af, B1h, acc1, 0, 0, 0);
        acc1 = __builtin_amdgcn_mfma_f32_16x16x32_bf16(Alo, B1h, acc1, 0, 0, 0);
        acc1 = __builtin_amdgcn_mfma_f32_16x16x32_bf16(Af, B1l, acc1, 0, 0, 0);
    }
#pragma unroll
    for (int r = 0; r < 4; ++r) {
        const int gs = gs0 + mt * 16 + lg * 4 + r;
        const int n = gs / Sc, s = gs - (gs / Sc) * Sc;
        const int t = n & 15, bb = n >> 4;
        const float v0 = acc0[r] + bias0;
        const float v1 = acc1[r] + bias1;
        const size_t rowbase = ((size_t)t * Bc + bb) * Kc;
        wxb[(rowbase + kA) * Sc + s] = v0;
        wxb[(rowbase + kA + 16) * Sc + s] = v1;
        if (t == 0) {
            const int px = (s / 14 + 1) * 16 + (s - (s / 14) * 14 + 1);
            const float a0 = (1.f - sigmoid_f(v0)) * tanh_f(v0);
            const float a1 = (1.f - sigmoid_f(v1)) * tanh_f(v1);
            assign0[((size_t)bb * Kc + kA) * Sc + s] = a0;
            assign0[((size_t)bb * Kc + kA + 16) * Sc + s] = a1;
            const size_t pp0 = (size_t)bb * PLB2 + (size_t)px * 64 + kA;
            hplane32[pp0] = a0; hplane16[pp0] = f2b(a0);
            hplane32[pp0 + 16] = a1; hplane16[pp0 + 16] = f2b(a1);
        }
    }
}

// ---------------- GRU gates via MFMA: grid (16 b, 2 mh, 2 gate), 512 thr = 8 Mt waves ----------------
// LDS plane [290][64] bf16, XOR-swizzled rows; conv-as-GEMM over 9 shifted taps
__global__ __launch_bounds__(512) void k_gru_gates(const unsigned short* __restrict__ hplane16,
        const float* __restrict__ wxb_t, const unsigned short* __restrict__ uth,
        const unsigned short* __restrict__ utl,
        float* __restrict__ zb, unsigned short* __restrict__ rhplane16) {
    __shared__ unsigned short P[290 * 64];
    const int b = blockIdx.x, mh = blockIdx.y, gate = blockIdx.z;
    const int tid = threadIdx.x;
    const int wv = tid >> 6, lane = tid & 63;
    const int lg = lane >> 4, ln = lane & 15;
    const int pxb = (mh * 8 + wv) * 16;

    int sE[4]; bool vE[4];
#pragma unroll
    for (int r = 0; r < 4; ++r) {
        int px = pxb + lg * 4 + r;
        int row = px >> 4, col = px & 15;
        vE[r] = (row >= 1 && row <= 14 && col >= 1 && col <= 14);
        sE[r] = vE[r] ? (row - 1) * 14 + col - 1 : 0;
    }
    float pre[4][4];
#pragma unroll
    for (int nt = 0; nt < 4; ++nt) {
        const float* wp = wxb_t + ((size_t)b * Kc + nt * 16 + ln) * Sc;
#pragma unroll
        for (int r = 0; r < 4; ++r) pre[nt][r] = vE[r] ? wp[sE[r]] : 0.f;
    }
    {   // guards + stage (linear read, swizzled write)
        const float4 z4 = make_float4(0.f, 0.f, 0.f, 0.f);
        float4* Pv = (float4*)P;
        if (tid < 136) { Pv[tid] = z4; Pv[273 * 8 + tid] = z4; }
        const float4* src = (const float4*)(hplane16 + (size_t)b * PLB2);
#pragma unroll
        for (int it = 0; it < 4; ++it) {
            int idx = it * 512 + tid;
            int px = idx >> 3, c16 = idx & 7;
            int row = px + 17;
            int boff = row * 128 + ((c16 * 16) ^ ((row & 7) << 4));
            *(float4*)((char*)P + boff) = src[idx];
        }
    }
    __syncthreads();

    const unsigned short* uh0 = uth + (size_t)gate * 9 * 4096;
    const unsigned short* ul0 = utl + (size_t)gate * 9 * 4096;
    f32x4 acc[4];
#pragma unroll
    for (int nt = 0; nt < 4; ++nt) acc[nt] = (f32x4){0.f, 0.f, 0.f, 0.f};
#pragma unroll
    for (int tap = 0; tap < 9; ++tap) {
        const int toff = (tap / 3 - 1) * 16 + (tap % 3 - 1);
#pragma unroll
        for (int ks = 0; ks < 2; ++ks) {
            const int row = pxb + ln + toff + 17;
            const int boff = row * 128 + ((ks * 64 + lg * 16) ^ ((row & 7) << 4));
            bf16x8 A = *(const bf16x8*)((const char*)P + boff);
#pragma unroll
            for (int nt = 0; nt < 4; ++nt) {
                const size_t bo = ((size_t)tap * 64 + nt * 16 + ln) * 64 + ks * 32 + lg * 8;
                bf16x8 Bh = *(const bf16x8*)(uh0 + bo);
                bf16x8 Bl = *(const bf16x8*)(ul0 + bo);
                acc[nt] = __builtin_amdgcn_mfma_f32_16x16x32_bf16(A, Bh, acc[nt], 0, 0, 0);
                acc[nt] = __builtin_amdgcn_mfma_f32_16x16x32_bf16(A, Bl, acc[nt], 0, 0, 0);
            }
        }
    }
#pragma unroll
    for (int nt = 0; nt < 4; ++nt) {
        const int ko = nt * 16 + ln;
#pragma unroll
        for (int r = 0; r < 4; ++r) {
            if (!vE[r]) continue;
            float sv = sigmoid_f(pre[nt][r] + acc[nt][r]);
            if (gate == 0) {
                zb[((size_t)b * Kc + ko) * Sc + sE[r]] = sv;
            } else {
                const int px = pxb + lg * 4 + r;
                const int row = px + 17;
                const int hoff = row * 128 + ((ko * 2) ^ ((row & 7) << 4));
                float hv = b2f(*(const unsigned short*)((const char*)P + hoff));
                rhplane16[(size_t)b * PLB2 + (size_t)px * 64 + ko] = f2b(sv * hv);
            }
        }
    }
}

// ---------------- GRU out via MFMA: grid (16 b, 2 mh, 2 nh), 512 thr ----------------
__global__ __launch_bounds__(512) void k_gru_out(const unsigned short* __restrict__ rhplane16,
        const float* __restrict__ wxb_t, const unsigned short* __restrict__ uth,
        const unsigned short* __restrict__ utl, const float* __restrict__ zb,
        float* __restrict__ hplane32, unsigned short* __restrict__ hplane16,
        float* __restrict__ assign_t) {
    __shared__ unsigned short P[290 * 64];
    const int b = blockIdx.x, mh = blockIdx.y, nh = blockIdx.z;
    const int tid = threadIdx.x;
    const int wv = tid >> 6, lane = tid & 63;
    const int lg = lane >> 4, ln = lane & 15;
    const int pxb = (mh * 8 + wv) * 16;

    int sE[4]; bool vE[4];
#pragma unroll
    for (int r = 0; r < 4; ++r) {
        int px = pxb + lg * 4 + r;
        int row = px >> 4, col = px & 15;
        vE[r] = (row >= 1 && row <= 14 && col >= 1 && col <= 14);
        sE[r] = vE[r] ? (row - 1) * 14 + col - 1 : 0;
    }
    float pre[2][4], zv[2][4], hp[2][4];
#pragma unroll
    for (int q = 0; q < 2; ++q) {
        const int ko = (nh * 2 + q) * 16 + ln;
        const float* wp = wxb_t + ((size_t)b * Kc + ko) * Sc;
        const float* zp = zb + ((size_t)b * Kc + ko) * Sc;
        const float* hpp = hplane32 + (size_t)b * PLB2 + ko;
#pragma unroll
        for (int r = 0; r < 4; ++r) {
            pre[q][r] = vE[r] ? wp[sE[r]] : 0.f;
            zv[q][r]  = vE[r] ? zp[sE[r]] : 0.f;
            hp[q][r]  = vE[r] ? hpp[(size_t)(pxb + lg * 4 + r) * 64] : 0.f;
        }
    }
    {
        const float4 z4 = make_float4(0.f, 0.f, 0.f, 0.f);
        float4* Pv = (float4*)P;
        if (tid < 136) { Pv[tid] = z4; Pv[273 * 8 + tid] = z4; }
        const float4* src = (const float4*)(rhplane16 + (size_t)b * PLB2);
#pragma unroll
        for (int it = 0; it < 4; ++it) {
            int idx = it * 512 + tid;
            int px = idx >> 3, c16 = idx & 7;
            int row = px + 17;
            int boff = row * 128 + ((c16 * 16) ^ ((row & 7) << 4));
            *(float4*)((char*)P + boff) = src[idx];
        }
    }
    __syncthreads();

    const unsigned short* uh0 = uth + (size_t)2 * 9 * 4096;   // Uh slot
    const unsigned short* ul0 = utl + (size_t)2 * 9 * 4096;
    f32x4 acc[2];
    acc[0] = (f32x4){0.f, 0.f, 0.f, 0.f};
    acc[1] = (f32x4){0.f, 0.f, 0.f, 0.f};
#pragma unroll
    for (int tap = 0; tap < 9; ++tap) {
        const int toff = (tap / 3 - 1) * 16 + (tap % 3 - 1);
#pragma unroll
        for (int ks = 0; ks < 2; ++ks) {
            const int row = pxb + ln + toff + 17;
            const int boff = row * 128 + ((ks * 64 + lg * 16) ^ ((row & 7) << 4));
            bf16x8 A = *(const bf16x8*)((const char*)P + boff);
#pragma unroll
            for (int q = 0; q < 2; ++q) {
                const size_t bo = ((size_t)tap * 64 + (nh * 2 + q) * 16 + ln) * 64 + ks * 32 + lg * 8;
                bf16x8 Bh = *(const bf16x8*)(uh0 + bo);
                bf16x8 Bl = *(const bf16x8*)(ul0 + bo);
                acc[q] = __builtin_amdgcn_mfma_f32_16x16x32_bf16(A, Bh, acc[q], 0, 0, 0);
                acc[q] = __builtin_amdgcn_mfma_f32_16x16x32_bf16(A, Bl, acc[q], 0, 0, 0);
            }
        }
    }
#pragma unroll
    for (int q = 0; q < 2; ++q) {
        const int ko = (nh * 2 + q) * 16 + ln;
#pragma unroll
        for (int r = 0; r < 4; ++r) {
            if (!vE[r]) continue;
            const int px = pxb + lg * 4 + r;
            float hh = tanh_f(pre[q][r] + acc[q][r]);
            float hn = (1.f - zv[q][r]) * hh + zv[q][r] * hp[q][r];
            const size_t pp = (size_t)b * PLB2 + (size_t)px * 64 + ko;
            hplane32[pp] = hn;
            hplane16[pp] = f2b(hn);
            assign_t[((size_t)b * Kc + ko) * Sc + sE[r]] = hn;
        }
    }
}

// ---------------- einsum via MFMA (unchanged) ----------------
__global__ __launch_bounds__(512) void k_einsum(const float* __restrict__ x, const float* __restrict__ assign,
                                                float* __restrict__ part) {
    extern __shared__ float lds[];
    unsigned short* Ah = (unsigned short*)lds;
    unsigned short* Al = Ah + 64 * 40;
    unsigned short* Xh = Al + 64 * 40;
    unsigned short* Xl = Xh + 128 * 40;
    const int cq = blockIdx.x, tg = blockIdx.y, b = blockIdx.z;
    const int tid = threadIdx.x;
    const int wv = tid >> 6, lane = tid & 63;
    const int lg = lane >> 4, ln = lane & 15;
    const int ka = tid >> 3, ss4 = (tid & 7) * 4;
    const int cx = tid >> 2, ss8 = (tid & 3) * 8;

    f32x4 acc[4];
#pragma unroll
    for (int mt = 0; mt < 4; ++mt) acc[mt] = (f32x4){0.f, 0.f, 0.f, 0.f};

    for (int tt = 0; tt < 2; ++tt) {
        const int t = tg * 2 + tt;
        const int n = b * Tc + t;
        const float* ap = assign + ((size_t)t * Bc + b) * KS;
        const float* xp = x + ((size_t)n * Cc + cq * 128) * Sc;
        for (int sc7 = 0; sc7 < 7; ++sc7) {
            const int s0 = sc7 * 32;
            __syncthreads();
            {
                float4 v = make_float4(0.f, 0.f, 0.f, 0.f);
                if (s0 + ss4 <= 192) v = *(const float4*)(ap + (size_t)ka * Sc + s0 + ss4);
                ushort4 h, l;
                split1(v.x, h.x, l.x); split1(v.y, h.y, l.y);
                split1(v.z, h.z, l.z); split1(v.w, h.w, l.w);
                *(ushort4*)(Ah + ka * 40 + ss4) = h;
                *(ushort4*)(Al + ka * 40 + ss4) = l;
            }
#pragma unroll
            for (int q = 0; q < 2; ++q) {
                const int so = ss8 + q * 4;
                float4 v = make_float4(0.f, 0.f, 0.f, 0.f);
                if (s0 + so <= 192) v = *(const float4*)(xp + (size_t)cx * Sc + s0 + so);
                ushort4 h, l;
                split1(v.x, h.x, l.x); split1(v.y, h.y, l.y);
                split1(v.z, h.z, l.z); split1(v.w, h.w, l.w);
                *(ushort4*)(Xh + cx * 40 + so) = h;
                *(ushort4*)(Xl + cx * 40 + so) = l;
            }
            __syncthreads();
            bf16x8 Bh = *(const bf16x8*)(Xh + (wv * 16 + ln) * 40 + lg * 8);
            bf16x8 Bl = *(const bf16x8*)(Xl + (wv * 16 + ln) * 40 + lg * 8);
#pragma unroll
            for (int mt = 0; mt < 4; ++mt) {
                bf16x8 Af = *(const bf16x8*)(Ah + (mt * 16 + ln) * 40 + lg * 8);
                bf16x8 Alo = *(const bf16x8*)(Al + (mt * 16 + ln) * 40 + lg * 8);
                acc[mt] = __builtin_amdgcn_mfma_f32_16x16x32_bf16(Af, Bh, acc[mt], 0, 0, 0);
                acc[mt] = __builtin_amdgcn_mfma_f32_16x16x32_bf16(Alo, Bh, acc[mt], 0, 0, 0);
                acc[mt] = __builtin_amdgcn_mfma_f32_16x16x32_bf16(Af, Bl, acc[mt], 0, 0, 0);
            }
        }
    }
    const int c = cq * 128 + wv * 16 + ln;
#pragma unroll
    for (int mt = 0; mt < 4; ++mt) {
#pragma unroll
        for (int r = 0; r < 4; ++r) {
            const int k = mt * 16 + lg * 4 + r;
            part[(((size_t)tg * Bc + b) * Kc + k) * Cc + c] = acc[mt][r];
        }
    }
}

// ---------------- reduce ----------------
__global__ __launch_bounds__(256) void k_reduce(const float* __restrict__ assign, const float* __restrict__ part,
        const float* __restrict__ centers, float* __restrict__ vlad, float* __restrict__ norm2) {
    __shared__ float redw[4];
    __shared__ float a_s;
    const int blk = blockIdx.x;
    const int b = blk >> 6, k = blk & 63;
    const int tid = threadIdx.x;
    const int wave = tid >> 6, lane = tid & 63;
    const size_t bkoff = ((size_t)b * Kc + k) * Sc;
    float s = 0.f;
    for (int q = tid; q < 784; q += 256) {
        int t = q / 49, s4 = q - t * 49;
        float4 v = *(const float4*)(assign + (size_t)t * BKS + bkoff + s4 * 4);
        s += (v.x + v.y) + (v.z + v.w);
    }
#pragma unroll
    for (int o = 1; o < 64; o <<= 1) s += __shfl_xor(s, o);
    if (lane == 0) redw[wave] = s;
    __syncthreads();
    if (tid == 0) a_s = redw[0] + redw[1] + redw[2] + redw[3];
    __syncthreads();
    const float a = a_s;
    const size_t base = ((size_t)b * Kc + k) * Cc;
    const int c = tid * 2;
    float2 acc2 = make_float2(0.f, 0.f);
#pragma unroll
    for (int g = 0; g < 8; ++g) {
        float2 p = *(const float2*)(part + (size_t)g * GFIN + base + c);
        acc2.x += p.x; acc2.y += p.y;
    }
    float2 cv = *(const float2*)(centers + (size_t)k * Cc + c);
    float v0 = acc2.x - a * cv.x, v1 = acc2.y - a * cv.y;
    *(float2*)(vlad + base + c) = make_float2(v0, v1);
    float ss = v0 * v0 + v1 * v1;
#pragma unroll
    for (int o = 1; o < 64; o <<= 1) ss += __shfl_xor(ss, o);
    __syncthreads();
    if (lane == 0) redw[wave] = ss;
    __syncthreads();
    if (tid == 0) norm2[blk] = redw[0] + redw[1] + redw[2] + redw[3];
}

// ---------------- norms ----------------
__global__ __launch_bounds__(64) void k_norms(const float* __restrict__ norm2, float* __restrict__ scl) {
    const int b = blockIdx.x;
    const int k = threadIdx.x;
    float ss = norm2[b * Kc + k];
    float inv = 1.f / fmaxf(sqrtf(ss), 1e-12f);
    float g = ss * inv * inv;
#pragma unroll
    for (int o = 1; o < 64; o <<= 1) g += __shfl_xor(g, o);
    float gi = 1.f / fmaxf(sqrtf(g), 1e-12f);
    scl[b * Kc + k] = inv * gi;
}

// ---------------- scale ----------------
__global__ __launch_bounds__(256) void k_scale(const float* __restrict__ vlad, const float* __restrict__ scl,
                                               float* __restrict__ out) {
    const int blk = blockIdx.x;
    const int b = blk >> 4, kt = blk & 15;
    const int tid = threadIdx.x;
    const int kk = tid >> 6, lane = tid & 63;
    const int k = kt * 4 + kk;
    const float sv = scl[b * Kc + k];
    const float* vp = vlad + ((size_t)b * Kc + k) * Cc + lane * 8;
    float* op = out + ((size_t)b * Kc + k) * Cc + lane * 8;
    float4 v0 = *(const float4*)vp;
    float4 v1 = *(const float4*)(vp + 4);
    *(float4*)op = make_float4(v0.x * sv, v0.y * sv, v0.z * sv, v0.w * sv);
    *(float4*)(op + 4) = make_float4(v1.x * sv, v1.y * sv, v1.z * sv, v1.w * sv);
}

extern "C" void kernel_launch(void* const* d_in, const int* in_sizes, int n_in,
                              void* d_out, int out_size, void* d_ws, size_t ws_size,
                              hipStream_t stream) {
    (void)in_sizes; (void)n_in; (void)out_size; (void)ws_size;
    const float* x       = (const float*)d_in[0];
    const float* centers = (const float*)d_in[1];
    const float* share_w = (const float*)d_in[2];
    const float* share_b = (const float*)d_in[3];
    const float* Uz      = (const float*)d_in[4];
    const float* Ur      = (const float*)d_in[5];
    const float* Uh      = (const float*)d_in[6];
    float* out = (float*)d_out;
    float* ws  = (float*)d_ws;

    float* part      = ws;
    float* vlad      = ws;
    float* wxb       = ws;
    unsigned short* rhplane16 = (unsigned short*)(ws + (size_t)TBKS);            // [B][256 px][64 k] bf16
    unsigned short* hplane16  = (unsigned short*)(ws + (size_t)TBKS + 131072);
    float* assign   = ws + (size_t)PART_N;
    float* zb       = assign + (size_t)TBKS;
    float* hplane32 = zb + (size_t)BKS;              // [B][px][k] fp32
    float* wreg     = hplane32 + (size_t)Bc * PLB2;
    unsigned short* w_hi = (unsigned short*)wreg;
    unsigned short* w_lo = w_hi + (size_t)Kc * Cc;
    unsigned short* utt_h = (unsigned short*)(wreg + (size_t)Kc * Cc / 2 * 2 / 2 + 16384);  // = wreg + 32768 floats? compute below
    // lay out cleanly in float units:
    //   wreg[0 .. 32768) floats = w_hi/w_lo (65536 ushorts)
    utt_h = (unsigned short*)(wreg + 32768);          // NUTT ushorts
    unsigned short* utt_l = utt_h + NUTT;             // NUTT ushorts (total 110592 floats for both)
    float* norm2    = wreg + 32768 + NUTT;            // NUTT u16 *2 = NUTT floats
    float* scl      = norm2 + (size_t)Bc * Kc;

    const size_t ein_lds = (64 * 40 + 128 * 40) * 2 * 2;       // 30.7 KB

    k_prep_w<<<dim3(128), 256, 0, stream>>>(share_w, w_hi, w_lo);
    k_prep_u<<<dim3(432), 256, 0, stream>>>(Uz, Ur, Uh, utt_h, utt_l);
    k_init<<<dim3(256), 256, 0, stream>>>((float4*)hplane32, (float4*)hplane16, (float4*)rhplane16);
    k_conv1x1<<<dim3(784), 512, 0, stream>>>(x, w_hi, w_lo, share_b, wxb,
                                             assign, hplane32, hplane16);
    for (int t = 1; t < Tc; ++t) {
        k_gru_gates<<<dim3(16, 2, 2), 512, 0, stream>>>(hplane16, wxb + (size_t)t * BKS,
                                                        utt_h, utt_l, zb, rhplane16);
        k_gru_out<<<dim3(16, 2, 2), 512, 0, stream>>>(rhplane16, wxb + (size_t)t * BKS,
                                                      utt_h, utt_l, zb, hplane32, hplane16,
                                                      assign + (size_t)t * BKS);
    }
    k_einsum<<<dim3(4, 8, 16), 512, ein_lds, stream>>>(x, assign, part);
    k_reduce<<<dim3(Bc * Kc), 256, 0, stream>>>(assign, part, centers, vlad, norm2);
    k_norms<<<dim3(Bc), 64, 0, stream>>>(norm2, scl);
    k_scale<<<dim3(256), 256, 0, stream>>>(vlad, scl, out);
}

// Round 15
// 455.661 us; speedup vs baseline: 2.1770x; 2.1770x over previous
//
#include <hip/hip_runtime.h>

#define Bc 16
#define Tc 16
#define Cc 512
#define Kc 64
#define Sc 196
#define KS (Kc*Sc)          // 12544
#define BKS (Bc*Kc*Sc)      // 200704
#define TBKS (Tc*BKS)       // 3211264
#define GFIN (16*64*512)    // 524288
#define PART_N (8*GFIN)     // 4194304
#define PX 256              // 16 rows * 16 cols per plane
#define PLB2 (Kc*PX)        // 16384 elems per b ([px][k] layout, k fastest)
#define NUTT 110592         // 3*9*64*64

typedef __attribute__((ext_vector_type(8))) short bf16x8;
typedef __attribute__((ext_vector_type(4))) float f32x4;

__device__ __forceinline__ float sigmoid_f(float x) { return 1.f / (1.f + __expf(-x)); }
__device__ __forceinline__ float tanh_f(float x) { return 1.f - 2.f / (__expf(2.f * x) + 1.f); }

__device__ __forceinline__ float b2f(unsigned short u) {
    return __uint_as_float(((unsigned)u) << 16);
}
__device__ __forceinline__ unsigned short f2b(float f) {   // RNE
    unsigned u = __float_as_uint(f);
    return (unsigned short)((u + 0x7FFFu + ((u >> 16) & 1u)) >> 16);
}
__device__ __forceinline__ void split1(float f, unsigned short& h, unsigned short& l) {
    unsigned u = __float_as_uint(f);
    unsigned uh = u & 0xffff0000u;
    h = (unsigned short)(uh >> 16);
    float fl = f - __uint_as_float(uh);
    l = (unsigned short)(__float_as_uint(fl) >> 16);
}

// ---------------- transpose share_w: wt[c][k] = w[k][c] ----------------
__global__ __launch_bounds__(256) void k_transpose_w(const float* __restrict__ w, float* __restrict__ wt) {
    int idx = blockIdx.x * 256 + threadIdx.x;
    if (idx < Kc * Cc) {
        int k = idx & 63, c = idx >> 6;
        wt[idx] = w[k * Cc + c];
    }
}

// ---------------- prep U: Utt[g][tap][ko][ki] hi/lo from U[ko][ki][tap] ----------------
__global__ __launch_bounds__(256) void k_prep_u(const float* __restrict__ Uz,
        const float* __restrict__ Ur, const float* __restrict__ Uh,
        unsigned short* __restrict__ uth, unsigned short* __restrict__ utl) {
    int idx = blockIdx.x * 256 + threadIdx.x;   // NUTT total (grid 432)
    int ki = idx & 63;
    int ko = (idx >> 6) & 63;
    int gt = idx >> 12;        // g*9 + tap
    int tap = gt % 9, g = gt / 9;
    const float* U = (g == 0) ? Uz : (g == 1) ? Ur : Uh;
    float v = U[((size_t)ko * 64 + ki) * 9 + tap];
    unsigned short h, l;
    split1(v, h, l);
    uth[idx] = h; utl[idx] = l;
}

// ---------------- zero-init planes ----------------
__global__ __launch_bounds__(256) void k_init(float4* __restrict__ h32,
        float4* __restrict__ h16, float4* __restrict__ rh16) {
    const int i = blockIdx.x * 256 + threadIdx.x;   // grid 256
    const float4 z = make_float4(0.f, 0.f, 0.f, 0.f);
    h32[i] = z;
    if (i < 32768) { h16[i] = z; rh16[i] = z; }
}

// ---------------- conv1x1 VALU (round-11 best) + fused GRU t=0 ----------------
__global__ __launch_bounds__(256) void k_conv1x1(const float* __restrict__ x, const float* __restrict__ wt,
        const float* __restrict__ bias, float* __restrict__ wxb,
        float* __restrict__ assign0, float* __restrict__ hplane32,
        unsigned short* __restrict__ hplane16) {
    __shared__ float Xs[64][64];
    const int tid = threadIdx.x;
    const int gs0 = blockIdx.x * 64;
    const int kw = __builtin_amdgcn_readfirstlane((tid >> 6) << 4);
    const int lane = tid & 63;
    const int rbase = (tid >> 6) * 16;
    const int gs_c = gs0 + lane;
    const int n_c = gs_c / Sc, s_c = gs_c - n_c * Sc;
    const float* xcol = x + (size_t)n_c * (Cc * Sc) + s_c;

    float xr[16];
#pragma unroll
    for (int q = 0; q < 16; ++q) xr[q] = xcol[(size_t)(rbase + q) * Sc];
    float acc[16] = {};
    for (int c0 = 0; c0 < Cc; c0 += 64) {
        __syncthreads();
#pragma unroll
        for (int q = 0; q < 16; ++q) Xs[rbase + q][lane] = xr[q];
        __syncthreads();
        if (c0 + 64 < Cc) {
#pragma unroll
            for (int q = 0; q < 16; ++q) xr[q] = xcol[(size_t)(c0 + 64 + rbase + q) * Sc];
        }
#pragma unroll 8
        for (int cc = 0; cc < 64; ++cc) {
            const float xv = Xs[cc][lane];
            const float* wp = wt + (size_t)(c0 + cc) * Kc + kw;   // wave-uniform -> s_load
#pragma unroll
            for (int i = 0; i < 16; ++i) acc[i] += wp[i] * xv;
        }
    }
    const int t = n_c & 15, bb = n_c >> 4;
    float* op = wxb + (((size_t)t * Bc + bb) * Kc + kw) * Sc + s_c;
    const int px0 = (s_c / 14 + 1) * 16 + (s_c - (s_c / 14) * 14 + 1);
#pragma unroll
    for (int i = 0; i < 16; ++i) {
        float v = acc[i] + bias[kw + i];
        op[(size_t)i * Sc] = v;
        if (t == 0) {   // fused GRU t=0: h = (1-sig(v))*tanh(v)
            float a = (1.f - sigmoid_f(v)) * tanh_f(v);
            assign0[((size_t)bb * Kc + kw + i) * Sc + s_c] = a;
            const size_t pp = (size_t)bb * PLB2 + (size_t)px0 * 64 + kw + i;
            hplane32[pp] = a; hplane16[pp] = f2b(a);
        }
    }
}

// ---------------- GRU gates v2: tap-GEMM MFMA, no LDS; grid (16 b, 14 row, 2 gate), 128 thr ----------------
__global__ __launch_bounds__(128) void k_gru_gates(const unsigned short* __restrict__ hplane16,
        const float* __restrict__ wxb_t, const unsigned short* __restrict__ uth,
        const unsigned short* __restrict__ utl,
        float* __restrict__ zb, unsigned short* __restrict__ rhplane16) {
    const int b = blockIdx.x, yrow = blockIdx.y + 1, gate = blockIdx.z;
    const int pxb = yrow * 16;
    const int tid = threadIdx.x;
    const int nh = tid >> 6;                 // wave = ko-half
    const int lane = tid & 63;
    const int lg = lane >> 4, ln = lane & 15;
    const unsigned short* hp = hplane16 + (size_t)b * PLB2;
    const unsigned short* ug_h = uth + (size_t)gate * 36864;
    const unsigned short* ug_l = utl + (size_t)gate * 36864;

    f32x4 acc[2];
    acc[0] = (f32x4){0.f, 0.f, 0.f, 0.f};
    acc[1] = (f32x4){0.f, 0.f, 0.f, 0.f};
#pragma unroll
    for (int tap = 0; tap < 9; ++tap) {
        const int toff = (tap / 3 - 1) * 16 + (tap % 3 - 1);
        int arow = pxb + ln + toff;
        arow = min(max(arow, 0), 255);       // clamped rows only feed discarded pad outputs
        const unsigned short* abase = hp + (size_t)arow * 64;
#pragma unroll
        for (int ks = 0; ks < 2; ++ks) {
            bf16x8 A = *(const bf16x8*)(abase + ks * 32 + lg * 8);
#pragma unroll
            for (int nt = 0; nt < 2; ++nt) {
                const int ko_t = (nh * 2 + nt) * 16;
                const size_t bo = ((size_t)tap * 64 + ko_t + ln) * 64 + ks * 32 + lg * 8;
                bf16x8 Bh = *(const bf16x8*)(ug_h + bo);
                bf16x8 Bl = *(const bf16x8*)(ug_l + bo);
                acc[nt] = __builtin_amdgcn_mfma_f32_16x16x32_bf16(A, Bh, acc[nt], 0, 0, 0);
                acc[nt] = __builtin_amdgcn_mfma_f32_16x16x32_bf16(A, Bl, acc[nt], 0, 0, 0);
            }
        }
    }
#pragma unroll
    for (int nt = 0; nt < 2; ++nt) {
        const int ko = (nh * 2 + nt) * 16 + ln;
#pragma unroll
        for (int r = 0; r < 4; ++r) {
            const int i = lg * 4 + r;        // column within row tile
            if (i >= 1 && i <= 14) {
                const int s = (yrow - 1) * 14 + (i - 1);
                const size_t cs = ((size_t)b * Kc + ko) * Sc + s;
                float sv = sigmoid_f(wxb_t[cs] + acc[nt][r]);
                if (gate == 0) {
                    zb[cs] = sv;
                } else {
                    const int px = pxb + i;
                    float hv = b2f(hp[(size_t)px * 64 + ko]);
                    rhplane16[(size_t)b * PLB2 + (size_t)px * 64 + ko] = f2b(sv * hv);
                }
            }
        }
    }
}

// ---------------- GRU out v2: grid (16 b, 14 row), 256 thr = 4 waves (ko quarters) ----------------
__global__ __launch_bounds__(256) void k_gru_out(const unsigned short* __restrict__ rhplane16,
        const float* __restrict__ wxb_t, const unsigned short* __restrict__ uth,
        const unsigned short* __restrict__ utl, const float* __restrict__ zb,
        float* __restrict__ hplane32, unsigned short* __restrict__ hplane16,
        float* __restrict__ assign_t) {
    const int b = blockIdx.x, yrow = blockIdx.y + 1;
    const int pxb = yrow * 16;
    const int tid = threadIdx.x;
    const int nt = tid >> 6;                 // wave = ko-quarter
    const int lane = tid & 63;
    const int lg = lane >> 4, ln = lane & 15;
    const unsigned short* rp = rhplane16 + (size_t)b * PLB2;
    const unsigned short* uh0 = uth + (size_t)2 * 36864;
    const unsigned short* ul0 = utl + (size_t)2 * 36864;

    f32x4 acc = (f32x4){0.f, 0.f, 0.f, 0.f};
#pragma unroll
    for (int tap = 0; tap < 9; ++tap) {
        const int toff = (tap / 3 - 1) * 16 + (tap % 3 - 1);
        int arow = pxb + ln + toff;
        arow = min(max(arow, 0), 255);
        const unsigned short* abase = rp + (size_t)arow * 64;
#pragma unroll
        for (int ks = 0; ks < 2; ++ks) {
            bf16x8 A = *(const bf16x8*)(abase + ks * 32 + lg * 8);
            const size_t bo = ((size_t)tap * 64 + nt * 16 + ln) * 64 + ks * 32 + lg * 8;
            bf16x8 Bh = *(const bf16x8*)(uh0 + bo);
            bf16x8 Bl = *(const bf16x8*)(ul0 + bo);
            acc = __builtin_amdgcn_mfma_f32_16x16x32_bf16(A, Bh, acc, 0, 0, 0);
            acc = __builtin_amdgcn_mfma_f32_16x16x32_bf16(A, Bl, acc, 0, 0, 0);
        }
    }
    const int ko = nt * 16 + ln;
#pragma unroll
    for (int r = 0; r < 4; ++r) {
        const int i = lg * 4 + r;
        if (i >= 1 && i <= 14) {
            const int s = (yrow - 1) * 14 + (i - 1);
            const size_t cs = ((size_t)b * Kc + ko) * Sc + s;
            const int px = pxb + i;
            const size_t pp = (size_t)b * PLB2 + (size_t)px * 64 + ko;
            float pre = wxb_t[cs];
            float zv = zb[cs];
            float hpv = hplane32[pp];
            float hh = tanh_f(pre + acc[r]);
            float hn = (1.f - zv) * hh + zv * hpv;
            hplane32[pp] = hn;
            hplane16[pp] = f2b(hn);
            assign_t[cs] = hn;
        }
    }
}

// ---------------- einsum via MFMA (round-13) ----------------
__global__ __launch_bounds__(512) void k_einsum(const float* __restrict__ x, const float* __restrict__ assign,
                                                float* __restrict__ part) {
    extern __shared__ float lds[];
    unsigned short* Ah = (unsigned short*)lds;
    unsigned short* Al = Ah + 64 * 40;
    unsigned short* Xh = Al + 64 * 40;
    unsigned short* Xl = Xh + 128 * 40;
    const int cq = blockIdx.x, tg = blockIdx.y, b = blockIdx.z;
    const int tid = threadIdx.x;
    const int wv = tid >> 6, lane = tid & 63;
    const int lg = lane >> 4, ln = lane & 15;
    const int ka = tid >> 3, ss4 = (tid & 7) * 4;
    const int cx = tid >> 2, ss8 = (tid & 3) * 8;

    f32x4 acc[4];
#pragma unroll
    for (int mt = 0; mt < 4; ++mt) acc[mt] = (f32x4){0.f, 0.f, 0.f, 0.f};

    for (int tt = 0; tt < 2; ++tt) {
        const int t = tg * 2 + tt;
        const int n = b * Tc + t;
        const float* ap = assign + ((size_t)t * Bc + b) * KS;
        const float* xp = x + ((size_t)n * Cc + cq * 128) * Sc;
        for (int sc7 = 0; sc7 < 7; ++sc7) {
            const int s0 = sc7 * 32;
            __syncthreads();
            {
                float4 v = make_float4(0.f, 0.f, 0.f, 0.f);
                if (s0 + ss4 <= 192) v = *(const float4*)(ap + (size_t)ka * Sc + s0 + ss4);
                ushort4 h, l;
                split1(v.x, h.x, l.x); split1(v.y, h.y, l.y);
                split1(v.z, h.z, l.z); split1(v.w, h.w, l.w);
                *(ushort4*)(Ah + ka * 40 + ss4) = h;
                *(ushort4*)(Al + ka * 40 + ss4) = l;
            }
#pragma unroll
            for (int q = 0; q < 2; ++q) {
                const int so = ss8 + q * 4;
                float4 v = make_float4(0.f, 0.f, 0.f, 0.f);
                if (s0 + so <= 192) v = *(const float4*)(xp + (size_t)cx * Sc + s0 + so);
                ushort4 h, l;
                split1(v.x, h.x, l.x); split1(v.y, h.y, l.y);
                split1(v.z, h.z, l.z); split1(v.w, h.w, l.w);
                *(ushort4*)(Xh + cx * 40 + so) = h;
                *(ushort4*)(Xl + cx * 40 + so) = l;
            }
            __syncthreads();
            bf16x8 Bh = *(const bf16x8*)(Xh + (wv * 16 + ln) * 40 + lg * 8);
            bf16x8 Bl = *(const bf16x8*)(Xl + (wv * 16 + ln) * 40 + lg * 8);
#pragma unroll
            for (int mt = 0; mt < 4; ++mt) {
                bf16x8 Af = *(const bf16x8*)(Ah + (mt * 16 + ln) * 40 + lg * 8);
                bf16x8 Alo = *(const bf16x8*)(Al + (mt * 16 + ln) * 40 + lg * 8);
                acc[mt] = __builtin_amdgcn_mfma_f32_16x16x32_bf16(Af, Bh, acc[mt], 0, 0, 0);
                acc[mt] = __builtin_amdgcn_mfma_f32_16x16x32_bf16(Alo, Bh, acc[mt], 0, 0, 0);
                acc[mt] = __builtin_amdgcn_mfma_f32_16x16x32_bf16(Af, Bl, acc[mt], 0, 0, 0);
            }
        }
    }
    const int c = cq * 128 + wv * 16 + ln;
#pragma unroll
    for (int mt = 0; mt < 4; ++mt) {
#pragma unroll
        for (int r = 0; r < 4; ++r) {
            const int k = mt * 16 + lg * 4 + r;
            part[(((size_t)tg * Bc + b) * Kc + k) * Cc + c] = acc[mt][r];
        }
    }
}

// ---------------- reduce ----------------
__global__ __launch_bounds__(256) void k_reduce(const float* __restrict__ assign, const float* __restrict__ part,
        const float* __restrict__ centers, float* __restrict__ vlad, float* __restrict__ norm2) {
    __shared__ float redw[4];
    __shared__ float a_s;
    const int blk = blockIdx.x;
    const int b = blk >> 6, k = blk & 63;
    const int tid = threadIdx.x;
    const int wave = tid >> 6, lane = tid & 63;
    const size_t bkoff = ((size_t)b * Kc + k) * Sc;
    float s = 0.f;
    for (int q = tid; q < 784; q += 256) {
        int t = q / 49, s4 = q - t * 49;
        float4 v = *(const float4*)(assign + (size_t)t * BKS + bkoff + s4 * 4);
        s += (v.x + v.y) + (v.z + v.w);
    }
#pragma unroll
    for (int o = 1; o < 64; o <<= 1) s += __shfl_xor(s, o);
    if (lane == 0) redw[wave] = s;
    __syncthreads();
    if (tid == 0) a_s = redw[0] + redw[1] + redw[2] + redw[3];
    __syncthreads();
    const float a = a_s;
    const size_t base = ((size_t)b * Kc + k) * Cc;
    const int c = tid * 2;
    float2 acc2 = make_float2(0.f, 0.f);
#pragma unroll
    for (int g = 0; g < 8; ++g) {
        float2 p = *(const float2*)(part + (size_t)g * GFIN + base + c);
        acc2.x += p.x; acc2.y += p.y;
    }
    float2 cv = *(const float2*)(centers + (size_t)k * Cc + c);
    float v0 = acc2.x - a * cv.x, v1 = acc2.y - a * cv.y;
    *(float2*)(vlad + base + c) = make_float2(v0, v1);
    float ss = v0 * v0 + v1 * v1;
#pragma unroll
    for (int o = 1; o < 64; o <<= 1) ss += __shfl_xor(ss, o);
    __syncthreads();
    if (lane == 0) redw[wave] = ss;
    __syncthreads();
    if (tid == 0) norm2[blk] = redw[0] + redw[1] + redw[2] + redw[3];
}

// ---------------- norms ----------------
__global__ __launch_bounds__(64) void k_norms(const float* __restrict__ norm2, float* __restrict__ scl) {
    const int b = blockIdx.x;
    const int k = threadIdx.x;
    float ss = norm2[b * Kc + k];
    float inv = 1.f / fmaxf(sqrtf(ss), 1e-12f);
    float g = ss * inv * inv;
#pragma unroll
    for (int o = 1; o < 64; o <<= 1) g += __shfl_xor(g, o);
    float gi = 1.f / fmaxf(sqrtf(g), 1e-12f);
    scl[b * Kc + k] = inv * gi;
}

// ---------------- scale ----------------
__global__ __launch_bounds__(256) void k_scale(const float* __restrict__ vlad, const float* __restrict__ scl,
                                               float* __restrict__ out) {
    const int blk = blockIdx.x;
    const int b = blk >> 4, kt = blk & 15;
    const int tid = threadIdx.x;
    const int kk = tid >> 6, lane = tid & 63;
    const int k = kt * 4 + kk;
    const float sv = scl[b * Kc + k];
    const float* vp = vlad + ((size_t)b * Kc + k) * Cc + lane * 8;
    float* op = out + ((size_t)b * Kc + k) * Cc + lane * 8;
    float4 v0 = *(const float4*)vp;
    float4 v1 = *(const float4*)(vp + 4);
    *(float4*)op = make_float4(v0.x * sv, v0.y * sv, v0.z * sv, v0.w * sv);
    *(float4*)(op + 4) = make_float4(v1.x * sv, v1.y * sv, v1.z * sv, v1.w * sv);
}

extern "C" void kernel_launch(void* const* d_in, const int* in_sizes, int n_in,
                              void* d_out, int out_size, void* d_ws, size_t ws_size,
                              hipStream_t stream) {
    (void)in_sizes; (void)n_in; (void)out_size; (void)ws_size;
    const float* x       = (const float*)d_in[0];
    const float* centers = (const float*)d_in[1];
    const float* share_w = (const float*)d_in[2];
    const float* share_b = (const float*)d_in[3];
    const float* Uz      = (const float*)d_in[4];
    const float* Ur      = (const float*)d_in[5];
    const float* Uh      = (const float*)d_in[6];
    float* out = (float*)d_out;
    float* ws  = (float*)d_ws;

    float* part      = ws;
    float* vlad      = ws;
    float* wxb       = ws;
    unsigned short* rhplane16 = (unsigned short*)(ws + (size_t)TBKS);            // [B][px][k] bf16
    unsigned short* hplane16  = (unsigned short*)(ws + (size_t)TBKS + 131072);
    float* assign   = ws + (size_t)PART_N;
    float* zb       = assign + (size_t)TBKS;
    float* hplane32 = zb + (size_t)BKS;              // [B][px][k] fp32
    float* wt       = hplane32 + (size_t)Bc * PLB2;  // [C][K] fp32 (32768 floats)
    unsigned short* utt_h = (unsigned short*)(wt + 32768);
    unsigned short* utt_l = utt_h + NUTT;
    float* norm2    = wt + 32768 + NUTT;             // 2*NUTT ushorts = NUTT floats
    float* scl      = norm2 + (size_t)Bc * Kc;

    const size_t ein_lds = (64 * 40 + 128 * 40) * 2 * 2;       // 30.7 KB

    k_transpose_w<<<dim3(128), 256, 0, stream>>>(share_w, wt);
    k_prep_u<<<dim3(432), 256, 0, stream>>>(Uz, Ur, Uh, utt_h, utt_l);
    k_init<<<dim3(256), 256, 0, stream>>>((float4*)hplane32, (float4*)hplane16, (float4*)rhplane16);
    k_conv1x1<<<dim3(784), 256, 0, stream>>>(x, wt, share_b, wxb, assign, hplane32, hplane16);
    for (int t = 1; t < Tc; ++t) {
        k_gru_gates<<<dim3(16, 14, 2), 128, 0, stream>>>(hplane16, wxb + (size_t)t * BKS,
                                                         utt_h, utt_l, zb, rhplane16);
        k_gru_out<<<dim3(16, 14), 256, 0, stream>>>(rhplane16, wxb + (size_t)t * BKS,
                                                    utt_h, utt_l, zb, hplane32, hplane16,
                                                    assign + (size_t)t * BKS);
    }
    k_einsum<<<dim3(4, 8, 16), 512, ein_lds, stream>>>(x, assign, part);
    k_reduce<<<dim3(Bc * Kc), 256, 0, stream>>>(assign, part, centers, vlad, norm2);
    k_norms<<<dim3(Bc), 64, 0, stream>>>(norm2, scl);
    k_scale<<<dim3(256), 256, 0, stream>>>(vlad, scl, out);
}